// Round 2
// baseline (180.206 us; speedup 1.0000x reference)
//
#include <hip/hip_runtime.h>

// HitTheMiddleModel: per-row physics sim + 1e-10 * tiny linear.
// R7 = R6 (shuffle-halo structure) + NONTEMPORAL streaming hints.
//   Input is read exactly once, output written exactly once and never re-read
//   by this kernel -> mark the center load and the float4 store `nt` so they
//   stream past L2/L3 (which the harness's 402MB poison fill trashes anyway).
//   Targets the cache write-allocate/evict path suspected of holding the
//   kernel at ~3.6 TB/s. Arithmetic and addresses are bit-identical to R6.
// Structure recap:
//   Thread q owns output float4 O4[q]. Inputs needed are floats 4q-2..4q+5,
//   i.e. window w2..w9 where w-index i <-> global float 4q-4+i:
//     one b128 nt load X4[q]    -> w4..w7  (floats 4q..4q+3)
//     w2,w3 = lane-1's C.z,C.w  -> __shfl_up by 1
//     w8,w9 = lane+1's C.x,C.y  -> __shfl_down by 1
//   Wave-edge lanes (0 and 63) fetch their 8B halo via ONE predicated global
//   load (2 active lanes/wave; normal, not nt).
//   Phase m = q%3 handled by cndmask selects (no divergence). No LDS tiles,
//   no barriers.
// Clamp safety: q==0 -> phase 0, w2/w3 unused; last q (n4=3*2^21) -> phase 2,
//   w8/w9 unused. Clamped junk is never consumed.
// Partial-wave safety: q clamped to n4-1 for loads/shuffles (all lanes stay
//   active so shuffles are well-defined); store predicated on q<n4; any lane
//   whose right neighbor is clamped takes the edge-load path.

typedef float v4f __attribute__((ext_vector_type(4)));

__device__ __forceinline__ void sim_row(float x0, float x1, float x2,
                                        const float* Wv, const float* bv,
                                        float& pos_o, float& vel_o, float& rew_o) {
    float vel = x1 + x2;
    float pos = x0 + vel;
    bool hit = (pos > 10.0f) || (pos < -10.0f);
    vel = hit ? -vel : vel;
    pos = fminf(10.0f, fmaxf(-10.0f, pos));
    float reward = -pos * pos;
    float y0 = fmaf(x0, Wv[0], fmaf(x1, Wv[1], fmaf(x2, Wv[2], bv[0])));
    float y1 = fmaf(x0, Wv[3], fmaf(x1, Wv[4], fmaf(x2, Wv[5], bv[1])));
    float y2 = fmaf(x0, Wv[6], fmaf(x1, Wv[7], fmaf(x2, Wv[8], bv[2])));
    pos_o = fmaf(1e-10f, y0, pos);
    vel_o = fmaf(1e-10f, y1, vel);
    rew_o = fmaf(1e-10f, y2, reward);
}

// 3-way select, branch-free (2 cndmask).
__device__ __forceinline__ float sel3(int m, float a, float b, float c) {
    float r = (m == 1) ? b : c;
    return (m == 0) ? a : r;
}

__global__ __launch_bounds__(256) void HitTheMiddleModel_kernel(
        const float4* __restrict__ X4,
        const float* __restrict__ X,
        const float* __restrict__ W,
        const float* __restrict__ B,
        float4* __restrict__ O4,
        long long n4, long long nfloats) {
    long long q = (long long)blockIdx.x * blockDim.x + threadIdx.x;
    long long qc = (q < n4) ? q : (n4 - 1);   // keep all lanes active for shuffles
    int lane = (int)(threadIdx.x & 63);

    float Wv[9];
#pragma unroll
    for (int i = 0; i < 9; ++i) Wv[i] = W[i];
    float bv[3] = {B[0], B[1], B[2]};

    // Single center load: 16B/lane, lane-contiguous, nontemporal (stream once).
    v4f C = __builtin_nontemporal_load((const v4f*)X4 + qc);

    // Halos from neighbor lanes' center loads.
    float w2 = __shfl_up(C.z, 1, 64);     // float 4q-2 (lane-1's C.z)
    float w3 = __shfl_up(C.w, 1, 64);     // float 4q-1
    float w8 = __shfl_down(C.x, 1, 64);   // float 4q+4 (lane+1's C.x)
    float w9 = __shfl_down(C.y, 1, 64);   // float 4q+5

    // Wave-edge lanes (and lanes whose right neighbor was clamped) fix up their
    // halo with one predicated 8B global load. 2 active lanes per full wave.
    bool leftEdge  = (lane == 0);
    bool rightEdge = (!leftEdge) && ((lane == 63) || (qc + 1 >= n4));
    if (leftEdge || rightEdge) {
        long long a;
        if (leftEdge) {
            a = 4 * qc - 2;                       // even -> 8B aligned
            if (a < 0) a = 0;                     // q==0: unused (phase 0)
        } else {
            a = 4 * qc + 4;
            if (a > nfloats - 2) a = nfloats - 2; // last q: unused (phase 2)
        }
        float2 e = *(const float2*)(X + a);
        if (leftEdge) { w2 = e.x; w3 = e.y; }
        else          { w8 = e.x; w9 = e.y; }
    }

    float w4 = C.x, w5 = C.y, w6 = C.z, w7 = C.w;

    int m = (int)((unsigned long long)qc % 3ull);

    // Row A covers output float 4q (component m); row B is the next row.
    float a0 = sel3(m, w4, w3, w2);
    float a1 = sel3(m, w5, w4, w3);
    float a2 = sel3(m, w6, w5, w4);
    float b0 = sel3(m, w7, w6, w5);
    float b1 = sel3(m, w8, w7, w6);
    float b2 = sel3(m, w9, w8, w7);

    float pA, vA, rA, pB, vB, rB;
    sim_row(a0, a1, a2, Wv, bv, pA, vA, rA);
    sim_row(b0, b1, b2, Wv, bv, pB, vB, rB);

    v4f r;
    r.x = sel3(m, pA, vA, rA);
    r.y = sel3(m, vA, rA, pB);
    r.z = sel3(m, rA, pB, vB);
    r.w = sel3(m, pB, vB, rB);
    if (q < n4) __builtin_nontemporal_store(r, (v4f*)O4 + q);
}

// Scalar tail for nfloats % 4 != 0 (never launched for B = 2^23).
__global__ void HitTheMiddleModel_tail(
        const float* __restrict__ X, const float* __restrict__ W,
        const float* __restrict__ B, float* __restrict__ O,
        long long startFloat, long long nfloats) {
    long long g = startFloat + (long long)blockIdx.x * blockDim.x + threadIdx.x;
    if (g >= nfloats) return;
    float Wv[9];
    for (int i = 0; i < 9; ++i) Wv[i] = W[i];
    float bv[3] = {B[0], B[1], B[2]};
    long long row = g / 3;
    int c = (int)(g % 3);
    float x0 = X[3 * row], x1 = X[3 * row + 1], x2 = X[3 * row + 2];
    float p, v, rw;
    sim_row(x0, x1, x2, Wv, bv, p, v, rw);
    O[g] = (c == 0) ? p : (c == 1) ? v : rw;
}

extern "C" void kernel_launch(void* const* d_in, const int* in_sizes, int n_in,
                              void* d_out, int out_size, void* d_ws, size_t ws_size,
                              hipStream_t stream) {
    const float* x = (const float*)d_in[0];
    const float* W = (const float*)d_in[1];
    const float* b = (const float*)d_in[2];
    float* out = (float*)d_out;

    long long nfloats = (long long)in_sizes[0];   // 3 * rows
    long long n4 = nfloats / 4;                   // full float4s

    const int block = 256;
    long long grid = (n4 + block - 1) / block;
    HitTheMiddleModel_kernel<<<(int)grid, block, 0, stream>>>(
        (const float4*)x, x, W, b, (float4*)out, n4, nfloats);

    long long startFloat = 4 * n4;
    if (startFloat < nfloats) {
        long long tailN = nfloats - startFloat;
        int tgrid = (int)((tailN + 255) / 256);
        HitTheMiddleModel_tail<<<tgrid, 256, 0, stream>>>(
            x, W, b, out, startFloat, nfloats);
    }
}

// Round 3
// 173.449 us; speedup vs baseline: 1.0390x; 1.0390x over previous
//
#include <hip/hip_runtime.h>

// HitTheMiddleModel: per-row physics sim + 1e-10 * tiny linear.
// R8 = revert R7's nontemporal hints -> back to R6 exactly (best measured:
//   173.68 us; R5 = 173.64 us). nt was neutral-to-negative (R7: 180.2 us in a
//   run with ~3 us/fill slower harness fills).
// Conclusion being tested: kernel is BW-roofline-bound (~32 us for 201 MB
//   unique traffic @ 6.3 TB/s); timed region is dominated by 2x ~59 us
//   harness poison fills + small reset dispatches. Kernel-side instruction
//   (R6) and cache-policy (R7) levers both produced zero delta.
// Structure:
//   Thread q owns output float4 O4[q]. Inputs needed are floats 4q-2..4q+5,
//   i.e. window w2..w9 where w-index i <-> global float 4q-4+i:
//     one b128 load X4[q]       -> w4..w7  (floats 4q..4q+3)
//     w2,w3 = lane-1's C.z,C.w  -> __shfl_up by 1
//     w8,w9 = lane+1's C.x,C.y  -> __shfl_down by 1
//   Wave-edge lanes (0 and 63) fetch their 8B halo via ONE predicated global
//   load (2 active lanes/wave). Phase m = q%3 handled by cndmask selects.
//   No LDS, no barriers.
// Clamp safety: q==0 -> phase 0, w2/w3 unused; last q (n4=3*2^21) -> phase 2,
//   w8/w9 unused. Clamped junk is never consumed.
// Partial-wave safety: q clamped to n4-1 for loads/shuffles (all lanes stay
//   active so shuffles are well-defined); store predicated on q<n4; any lane
//   whose right neighbor is clamped takes the edge-load path.

__device__ __forceinline__ void sim_row(float x0, float x1, float x2,
                                        const float* Wv, const float* bv,
                                        float& pos_o, float& vel_o, float& rew_o) {
    float vel = x1 + x2;
    float pos = x0 + vel;
    bool hit = (pos > 10.0f) || (pos < -10.0f);
    vel = hit ? -vel : vel;
    pos = fminf(10.0f, fmaxf(-10.0f, pos));
    float reward = -pos * pos;
    float y0 = fmaf(x0, Wv[0], fmaf(x1, Wv[1], fmaf(x2, Wv[2], bv[0])));
    float y1 = fmaf(x0, Wv[3], fmaf(x1, Wv[4], fmaf(x2, Wv[5], bv[1])));
    float y2 = fmaf(x0, Wv[6], fmaf(x1, Wv[7], fmaf(x2, Wv[8], bv[2])));
    pos_o = fmaf(1e-10f, y0, pos);
    vel_o = fmaf(1e-10f, y1, vel);
    rew_o = fmaf(1e-10f, y2, reward);
}

// 3-way select, branch-free (2 cndmask).
__device__ __forceinline__ float sel3(int m, float a, float b, float c) {
    float r = (m == 1) ? b : c;
    return (m == 0) ? a : r;
}

__global__ __launch_bounds__(256) void HitTheMiddleModel_kernel(
        const float4* __restrict__ X4,
        const float* __restrict__ X,
        const float* __restrict__ W,
        const float* __restrict__ B,
        float4* __restrict__ O4,
        long long n4, long long nfloats) {
    long long q = (long long)blockIdx.x * blockDim.x + threadIdx.x;
    long long qc = (q < n4) ? q : (n4 - 1);   // keep all lanes active for shuffles
    int lane = (int)(threadIdx.x & 63);

    float Wv[9];
#pragma unroll
    for (int i = 0; i < 9; ++i) Wv[i] = W[i];
    float bv[3] = {B[0], B[1], B[2]};

    // Single center load: 16B/lane, lane-contiguous.
    float4 C = X4[qc];

    // Halos from neighbor lanes' center loads.
    float w2 = __shfl_up(C.z, 1, 64);     // float 4q-2 (lane-1's C.z)
    float w3 = __shfl_up(C.w, 1, 64);     // float 4q-1
    float w8 = __shfl_down(C.x, 1, 64);   // float 4q+4 (lane+1's C.x)
    float w9 = __shfl_down(C.y, 1, 64);   // float 4q+5

    // Wave-edge lanes (and lanes whose right neighbor was clamped) fix up their
    // halo with one predicated 8B global load. 2 active lanes per full wave.
    bool leftEdge  = (lane == 0);
    bool rightEdge = (!leftEdge) && ((lane == 63) || (qc + 1 >= n4));
    if (leftEdge || rightEdge) {
        long long a;
        if (leftEdge) {
            a = 4 * qc - 2;                       // even -> 8B aligned
            if (a < 0) a = 0;                     // q==0: unused (phase 0)
        } else {
            a = 4 * qc + 4;
            if (a > nfloats - 2) a = nfloats - 2; // last q: unused (phase 2)
        }
        float2 e = *(const float2*)(X + a);
        if (leftEdge) { w2 = e.x; w3 = e.y; }
        else          { w8 = e.x; w9 = e.y; }
    }

    float w4 = C.x, w5 = C.y, w6 = C.z, w7 = C.w;

    int m = (int)((unsigned long long)qc % 3ull);

    // Row A covers output float 4q (component m); row B is the next row.
    float a0 = sel3(m, w4, w3, w2);
    float a1 = sel3(m, w5, w4, w3);
    float a2 = sel3(m, w6, w5, w4);
    float b0 = sel3(m, w7, w6, w5);
    float b1 = sel3(m, w8, w7, w6);
    float b2 = sel3(m, w9, w8, w7);

    float pA, vA, rA, pB, vB, rB;
    sim_row(a0, a1, a2, Wv, bv, pA, vA, rA);
    sim_row(b0, b1, b2, Wv, bv, pB, vB, rB);

    float4 r;
    r.x = sel3(m, pA, vA, rA);
    r.y = sel3(m, vA, rA, pB);
    r.z = sel3(m, rA, pB, vB);
    r.w = sel3(m, pB, vB, rB);
    if (q < n4) O4[q] = r;
}

// Scalar tail for nfloats % 4 != 0 (never launched for B = 2^23).
__global__ void HitTheMiddleModel_tail(
        const float* __restrict__ X, const float* __restrict__ W,
        const float* __restrict__ B, float* __restrict__ O,
        long long startFloat, long long nfloats) {
    long long g = startFloat + (long long)blockIdx.x * blockDim.x + threadIdx.x;
    if (g >= nfloats) return;
    float Wv[9];
    for (int i = 0; i < 9; ++i) Wv[i] = W[i];
    float bv[3] = {B[0], B[1], B[2]};
    long long row = g / 3;
    int c = (int)(g % 3);
    float x0 = X[3 * row], x1 = X[3 * row + 1], x2 = X[3 * row + 2];
    float p, v, rw;
    sim_row(x0, x1, x2, Wv, bv, p, v, rw);
    O[g] = (c == 0) ? p : (c == 1) ? v : rw;
}

extern "C" void kernel_launch(void* const* d_in, const int* in_sizes, int n_in,
                              void* d_out, int out_size, void* d_ws, size_t ws_size,
                              hipStream_t stream) {
    const float* x = (const float*)d_in[0];
    const float* W = (const float*)d_in[1];
    const float* b = (const float*)d_in[2];
    float* out = (float*)d_out;

    long long nfloats = (long long)in_sizes[0];   // 3 * rows
    long long n4 = nfloats / 4;                   // full float4s

    const int block = 256;
    long long grid = (n4 + block - 1) / block;
    HitTheMiddleModel_kernel<<<(int)grid, block, 0, stream>>>(
        (const float4*)x, x, W, b, (float4*)out, n4, nfloats);

    long long startFloat = 4 * n4;
    if (startFloat < nfloats) {
        long long tailN = nfloats - startFloat;
        int tgrid = (int)((tailN + 255) / 256);
        HitTheMiddleModel_tail<<<tgrid, 256, 0, stream>>>(
            x, W, b, out, startFloat, nfloats);
    }
}